// Round 9
// baseline (276.152 us; speedup 1.0000x reference)
//
#include <hip/hip_runtime.h>
#include <math.h>

#define BB 32
#define CC 256
#define TT 1024

typedef __attribute__((ext_vector_type(4))) float f4;
typedef __attribute__((ext_vector_type(4))) float f32x4;
typedef __attribute__((ext_vector_type(16))) float f32x16;
typedef __attribute__((ext_vector_type(8))) short s8;   // bf16x8 MFMA frag (4 VGPRs)
typedef __attribute__((ext_vector_type(4))) short s4v;  // 8B LDS store

__device__ inline short f2bf(float f) {                 // RNE fp32->bf16
    unsigned u = __builtin_bit_cast(unsigned, f);
    u = (u + 0x7FFFu + ((u >> 16) & 1u)) >> 16;
    return (short)u;
}

// ---- workspace layout (bytes) ----  total 76,873,728 B = 73.3 MB
static const size_t OFF_QBF  = 0;          // [B][T][64] bf16   4 MB
static const size_t OFF_KBF  = 4194304;    // [B][T][64] bf16   4 MB
static const size_t OFF_VT   = 8388608;    // [B][C][T]  bf16  16 MB (v transposed)
static const size_t OFF_OA   = 25165824;   // [B][T][C]: xt bf16 -> oa bf16 -> c2 fp32 (32 MB)
static const size_t OFF_C1   = 58720256;   // [B][T][C]  bf16  16 MB (conv1 out)
static const size_t OFF_CRZ  = 75497472;   // [B][T] fp32 col 1/Z          (131072 B)
static const size_t OFF_RS   = 75628544;   // [B][T] fp32 rowsum           (131072 B)
static const size_t OFF_WX   = 75759616;   // [B][T] fp32 weight_x         (131072 B)
static const size_t OFF_W1   = 75890688;   // [3][256][256] bf16 W1 [j][o][c]  (393216 B)
static const size_t OFF_W2   = 76283904;   // [3][256][256] bf16 W2            (393216 B)
static const size_t OFF_WQKV = 76677120;   // [384][256] bf16 (q|k|v) [n][c]   (196608 B)

// ---------------------------------------------------------------------------
__global__ __launch_bounds__(256)
void wn_kernel(const float* __restrict__ v1, const float* __restrict__ g1,
               const float* __restrict__ v2, const float* __restrict__ g2,
               short* __restrict__ w1bf, short* __restrict__ w2bf) {
    __shared__ float red[4];
    int which = blockIdx.x >> 8, o = blockIdx.x & 255;
    const float* v = which ? v2 : v1;
    const float* g = which ? g2 : g1;
    short* wt = which ? w2bf : w1bf;
    const float* row = v + (size_t)o * 768;
    int tid = threadIdx.x, lane = tid & 63, wv_ = tid >> 6;
    float r0 = row[tid], r1 = row[tid + 256], r2 = row[tid + 512];
    float s = r0 * r0 + r1 * r1 + r2 * r2;
    for (int d = 1; d < 64; d <<= 1) s += __shfl_xor(s, d, 64);
    if (lane == 0) red[wv_] = s;
    __syncthreads();
    float scale = g[o] * rsqrtf(red[0] + red[1] + red[2] + red[3]);
    for (int j = 0; j < 3; ++j)
        wt[((size_t)(j * 256 + o)) * 256 + tid] = f2bf(scale * row[tid * 3 + j]);
}

__global__ __launch_bounds__(256)
void pack_kernel(const float* __restrict__ wq, const float* __restrict__ wk,
                 const float* __restrict__ wv, short* __restrict__ wqkvbf) {
    int n = blockIdx.x * 4 + (threadIdx.x >> 6);
    int c0 = (threadIdx.x & 63) * 4;
    for (int p = 0; p < 4; ++p) {
        int c = c0 + p;
        float w;
        if (n < 64)       w = wq[c * 64 + n];
        else if (n < 128) w = wk[c * 64 + n - 64];
        else              w = wv[c * 256 + n - 128];
        wqkvbf[(size_t)n * 256 + c] = f2bf(w);
    }
}

// ---------------------------------------------------------------------------
__global__ void transpose_kernel(const float* __restrict__ x, short* __restrict__ xt) {
    __shared__ float Tt[64 * 68];
    int tid = threadIdx.x;
    int c0 = blockIdx.x * 64, t0 = blockIdx.y * 64, b = blockIdx.z;
    for (int it = 0; it < 4; ++it) {
        int idx = tid + 256 * it;
        int cr = idx >> 4, tc = idx & 15;
        f4 v = *reinterpret_cast<const f4*>(&x[((size_t)b * CC + c0 + cr) * TT + t0 + tc * 4]);
        *reinterpret_cast<f4*>(&Tt[cr * 68 + tc * 4]) = v;
    }
    __syncthreads();
    for (int it = 0; it < 2; ++it) {
        int idx = tid + 256 * it;
        int tl = idx >> 3, seg = idx & 7;
        s8 o;
        for (int p = 0; p < 8; ++p) o[p] = f2bf(Tt[(seg * 8 + p) * 68 + tl]);
        *reinterpret_cast<s8*>(&xt[((size_t)b * TT + t0 + tl) * CC + c0 + seg * 8]) = o;
    }
}

// ---------------------------------------------------------------------------
// qkv: 1D grid 1536, bid = q*48 + n*8 + r -> same-A blocks same XCD.
__global__ __launch_bounds__(256, 3)
void qkv_kernel(const short* __restrict__ xt, const short* __restrict__ wqkv,
                const float* __restrict__ bq, const float* __restrict__ bk,
                const float* __restrict__ bv,
                short* __restrict__ qbf, short* __restrict__ kbf, short* __restrict__ vt) {
    __shared__ short SL[128 * 72 + 64 * 72];   // A (128t x 64c) then B (64n x 64c)
    short* Asm = SL;
    short* Bsm = SL + 128 * 72;
    int tid = threadIdx.x, wv_ = tid >> 6, lane = tid & 63;
    int n15 = lane & 15, quad = lane >> 4;
    int bid = blockIdx.x;
    int r = bid & 7, n = (bid >> 3) % 6, qd = bid / 48;
    int bt = qd * 8 + r;
    int b = bt >> 3, t0 = (bt & 7) * 128;
    int n0 = n * 64;

    f32x4 acc[2][4];
    for (int i = 0; i < 2; ++i) for (int j = 0; j < 4; ++j)
        for (int p = 0; p < 4; ++p) acc[i][j][p] = 0.f;

    for (int kc = 0; kc < 4; ++kc) {
        int c0 = kc * 64;
        __syncthreads();
        for (int it = 0; it < 4; ++it) {
            int idx = tid + 256 * it;
            int row = idx >> 3, seg = idx & 7;
            *reinterpret_cast<s8*>(&Asm[row * 72 + seg * 8]) =
                *reinterpret_cast<const s8*>(&xt[((size_t)b * TT + t0 + row) * CC + c0 + seg * 8]);
        }
        for (int it = 0; it < 2; ++it) {
            int idx = tid + 256 * it;
            int row = idx >> 3, seg = idx & 7;
            *reinterpret_cast<s8*>(&Bsm[row * 72 + seg * 8]) =
                *reinterpret_cast<const s8*>(&wqkv[(size_t)(n0 + row) * 256 + c0 + seg * 8]);
        }
        __syncthreads();
        for (int ks = 0; ks < 2; ++ks)
            for (int mt2 = 0; mt2 < 2; ++mt2) {
                s8 a = *reinterpret_cast<const s8*>(&Asm[(wv_ * 32 + mt2 * 16 + n15) * 72 + quad * 8 + ks * 32]);
                for (int nt = 0; nt < 4; ++nt) {
                    s8 bb = *reinterpret_cast<const s8*>(&Bsm[(nt * 16 + n15) * 72 + quad * 8 + ks * 32]);
                    acc[mt2][nt] = __builtin_amdgcn_mfma_f32_16x16x32_bf16(a, bb, acc[mt2][nt], 0, 0, 0);
                }
            }
    }
    if (n0 < 128) {
        short* outp = (n0 == 0) ? qbf : kbf;
        const float* bias = (n0 == 0) ? bq : bk;
        for (int mt2 = 0; mt2 < 2; ++mt2)
            for (int nt = 0; nt < 4; ++nt) {
                int n_ = nt * 16 + n15;
                float bvl = bias[n_];
                for (int reg = 0; reg < 4; ++reg) {
                    int t = t0 + wv_ * 32 + mt2 * 16 + quad * 4 + reg;
                    outp[((size_t)b * TT + t) * 64 + n_] = f2bf(acc[mt2][nt][reg] + bvl);
                }
            }
    } else {
        int cbase = n0 - 128;
        __syncthreads();
        short* Tw = SL + wv_ * 3072;
        for (int mt2 = 0; mt2 < 2; ++mt2)
            for (int nt = 0; nt < 4; ++nt) {
                int n_ = nt * 16 + n15;
                float bvl = bv[cbase + n_];
                for (int reg = 0; reg < 4; ++reg)
                    Tw[n_ * 48 + mt2 * 16 + quad * 4 + reg] = f2bf(acc[mt2][nt][reg] + bvl);
            }
        for (int p = 0; p < 4; ++p) {
            int n_ = (lane >> 2) + 16 * p;
            int seg = lane & 3;
            s8 vv = *reinterpret_cast<const s8*>(&Tw[n_ * 48 + seg * 8]);
            *reinterpret_cast<s8*>(&vt[((size_t)b * CC + cbase + n_) * TT + t0 + wv_ * 32 + seg * 8]) = vv;
        }
    }
}

// ---------------------------------------------------------------------------
// colz R9: grid 512, ONE kt per block. bid pairing: b=bid&31 (XCD locality),
// j=bid>>5, kt = j<8 ? j : 23-j -> blocks bid and bid+256 land on the same CU
// (round-robin over 256 CUs) and their iter counts sum to 17 -> balance AND
// 2 blocks/CU = 16 waves/CU (R8 had 1 block/CU = 8 waves, 42% busy).
__global__ __launch_bounds__(512, 2)
void colz_kernel(const short* __restrict__ qbf, const short* __restrict__ kbf,
                 float* __restrict__ colrz) {
    __shared__ short Qs[64 * 72], Ks[64 * 72];
    __shared__ float redz[8 * 32];
    int tid = threadIdx.x, wv_ = tid >> 6, lane = tid & 63;
    int l31 = lane & 31, lh = lane >> 5;
    int qhalf = wv_ & 1, khalf = (wv_ >> 1) & 1, w4 = wv_ >> 2;
    int b = blockIdx.x & 31, j = blockIdx.x >> 5;
    int kt = (j < 8) ? j : 23 - j;
    int row = tid >> 3, sg = (tid & 7) * 8;

    s8 kr0 = *reinterpret_cast<const s8*>(&kbf[((size_t)b * TT + kt * 64 + row) * 64 + sg]);
    s8 qr0 = *reinterpret_cast<const s8*>(&qbf[((size_t)b * TT + kt * 64 + row) * 64 + sg]);
    float zloc = 0.f;
    for (int qt = kt; qt < 16; ++qt) {
        __syncthreads();
        if (qt == kt) *reinterpret_cast<s8*>(&Ks[row * 72 + sg]) = kr0;
        *reinterpret_cast<s8*>(&Qs[row * 72 + sg]) = qr0;
        __syncthreads();
        if (qt < 15)
            qr0 = *reinterpret_cast<const s8*>(&qbf[((size_t)b * TT + (qt + 1) * 64 + row) * 64 + sg]);
        f32x16 s;
        for (int p = 0; p < 16; ++p) s[p] = 0.f;
        for (int kc = 0; kc < 4; ++kc) {
            s8 a  = *reinterpret_cast<const s8*>(&Qs[(qhalf * 32 + l31) * 72 + kc * 16 + lh * 8]);
            s8 bb = *reinterpret_cast<const s8*>(&Ks[(khalf * 32 + l31) * 72 + kc * 16 + lh * 8]);
            s = __builtin_amdgcn_mfma_f32_32x32x16_bf16(a, bb, s, 0, 0, 0);
        }
        int kg = kt * 64 + khalf * 32 + l31;
        int qb0 = qt * 64 + qhalf * 32 + 4 * lh;
        if (qt > kt) {
            for (int r = 0; r < 8; ++r) {
                int reg = w4 * 8 + r;
                zloc += __expf(s[reg] * 0.125f);
            }
        } else {
            for (int r = 0; r < 8; ++r) {
                int reg = w4 * 8 + r;
                if (qb0 + (reg & 3) + 8 * (reg >> 2) >= kg) zloc += __expf(s[reg] * 0.125f);
            }
        }
    }
    float zc = zloc + __shfl_xor(zloc, 32, 64);
    if (lane < 32) redz[wv_ * 32 + lane] = zc;
    __syncthreads();
    if (tid < 64) {
        int kh = tid >> 5, kk = tid & 31;
        float Z;
        if (kh == 0) Z = redz[0 * 32 + kk] + redz[1 * 32 + kk] + redz[4 * 32 + kk] + redz[5 * 32 + kk];
        else         Z = redz[2 * 32 + kk] + redz[3 * 32 + kk] + redz[6 * 32 + kk] + redz[7 * 32 + kk];
        colrz[(size_t)b * TT + kt * 64 + tid] = 1.0f / Z;
    }
}

// ---------------------------------------------------------------------------
// attn R9: grid 512, ONE qt per block; b=bid&31 keeps XCD locality (13 MB
// fetch), j=bid>>5, qt = j<8 ? 15-j : j-8 -> paired blocks bid/bid+256 share
// a CU: balance + 2 blocks/CU = 16 waves/CU (4/SIMD latency hiding).
__global__ __launch_bounds__(512, 2)
void attn_kernel(const short* __restrict__ qbf, const short* __restrict__ kbf,
                 const short* __restrict__ vt, const float* __restrict__ colrz,
                 short* __restrict__ oab, float* __restrict__ rowsum) {
    __shared__ short Qs[64 * 72];
    __shared__ short Ks[64 * 72];
    __shared__ short Ps[64 * 72];   // [q][k] bf16, PV A-operand (cross-wave)
    __shared__ short Vs[256 * 72];  // [c][t_k] bf16, PV B-operand
    __shared__ float redR[2][64];
    int tid = threadIdx.x, wv_ = tid >> 6, lane = tid & 63;
    int l31 = lane & 31, lh = lane >> 5;
    int wq2 = wv_ & 1, wk2 = (wv_ >> 1) & 1, w4 = wv_ >> 2, wcq = wv_ >> 1;
    int b = blockIdx.x & 31, j = blockIdx.x >> 5;
    int qt = (j < 8) ? 15 - j : j - 8;
    int row = tid >> 3, sg = (tid & 7) * 8;

    s8 kreg, vreg[4];
    {   // K/V tile kt=0
        kreg = *reinterpret_cast<const s8*>(&kbf[((size_t)b * TT + row) * 64 + sg]);
        for (int it = 0; it < 4; ++it) {
            int idx = tid + 512 * it;
            int vr = idx >> 3, seg = idx & 7;
            vreg[it] = *reinterpret_cast<const s8*>(&vt[((size_t)b * CC + vr) * TT + seg * 8]);
        }
    }
    s8 qr0 = *reinterpret_cast<const s8*>(&qbf[((size_t)b * TT + qt * 64 + row) * 64 + sg]);
    f32x16 acc[2];
    for (int i = 0; i < 2; ++i) for (int p = 0; p < 16; ++p) acc[i][p] = 0.f;
    float rsum[8];
    for (int i = 0; i < 8; ++i) rsum[i] = 0.f;

    for (int kt = 0; kt <= qt; ++kt) {
        __syncthreads();
        if (kt == 0) *reinterpret_cast<s8*>(&Qs[row * 72 + sg]) = qr0;
        *reinterpret_cast<s8*>(&Ks[row * 72 + sg]) = kreg;
        for (int it = 0; it < 4; ++it) {
            int idx = tid + 512 * it;
            int vr = idx >> 3, seg = idx & 7;
            *reinterpret_cast<s8*>(&Vs[vr * 72 + seg * 8]) = vreg[it];
        }
        __syncthreads();
        if (kt < qt) {   // prefetch overlaps compute below
            kreg = *reinterpret_cast<const s8*>(&kbf[((size_t)b * TT + (kt + 1) * 64 + row) * 64 + sg]);
            for (int it = 0; it < 4; ++it) {
                int idx = tid + 512 * it;
                int vr = idx >> 3, seg = idx & 7;
                vreg[it] = *reinterpret_cast<const s8*>(&vt[((size_t)b * CC + vr) * TT + (kt + 1) * 64 + seg * 8]);
            }
        }
        // QK quadrant (wq2, wk2), duplicated across w4 pair: 4 MFMAs
        f32x16 s;
        for (int p = 0; p < 16; ++p) s[p] = 0.f;
        for (int kc = 0; kc < 4; ++kc) {
            s8 a  = *reinterpret_cast<const s8*>(&Qs[(wq2 * 32 + l31) * 72 + kc * 16 + lh * 8]);
            s8 bb = *reinterpret_cast<const s8*>(&Ks[(wk2 * 32 + l31) * 72 + kc * 16 + lh * 8]);
            s = __builtin_amdgcn_mfma_f32_32x32x16_bf16(a, bb, s, 0, 0, 0);
        }
        int kg = kt * 64 + wk2 * 32 + l31;
        float rz = colrz[(size_t)b * TT + kg];
        bool full = (kt < qt);
        int qb0 = qt * 64 + wq2 * 32 + 4 * lh;
        for (int r = 0; r < 8; ++r) {      // exp split: w4 half of the regs
            int reg = w4 * 8 + r;
            int rr = (reg & 3) + 8 * (reg >> 2);
            float p = 0.f;
            if (full || qb0 + rr >= kg) p = __expf(s[reg] * 0.125f) * rz;
            rsum[r] += p;
            Ps[(wq2 * 32 + rr + 4 * lh) * 72 + wk2 * 32 + l31] = f2bf(p);
        }
        __syncthreads();   // Ps cross-wave
        // PV: q half wq2 x c quarter wcq: 2 tiles x 4 kc = 8 MFMAs
        for (int kc = 0; kc < 4; ++kc) {
            s8 a = *reinterpret_cast<const s8*>(&Ps[(wq2 * 32 + l31) * 72 + kc * 16 + lh * 8]);
            for (int nt = 0; nt < 2; ++nt) {
                s8 bb = *reinterpret_cast<const s8*>(&Vs[(wcq * 64 + nt * 32 + l31) * 72 + kc * 16 + lh * 8]);
                acc[nt] = __builtin_amdgcn_mfma_f32_32x32x16_bf16(a, bb, acc[nt], 0, 0, 0);
            }
        }
    }
    // rowsum: butterfly over the 32 k-columns, then combine wk2 halves
    for (int r = 0; r < 8; ++r) {
        float v = rsum[r];
        v += __shfl_xor(v, 1, 64);
        v += __shfl_xor(v, 2, 64);
        v += __shfl_xor(v, 4, 64);
        v += __shfl_xor(v, 8, 64);
        v += __shfl_xor(v, 16, 64);
        int reg = w4 * 8 + r;
        int rr = (reg & 3) + 8 * (reg >> 2);
        if (l31 == 0) redR[wk2][wq2 * 32 + rr + 4 * lh] = v;
    }
    for (int nt = 0; nt < 2; ++nt) {
        int c = wcq * 64 + nt * 32 + l31;
        for (int reg = 0; reg < 16; ++reg) {
            int q = qt * 64 + wq2 * 32 + (reg & 3) + 8 * (reg >> 2) + 4 * lh;
            oab[((size_t)b * TT + q) * CC + c] = f2bf(acc[nt][reg]);
        }
    }
    __syncthreads();
    if (tid < 64) rowsum[(size_t)b * TT + qt * 64 + tid] = redR[0][tid] + redR[1][tid];
}

// ---------------------------------------------------------------------------
// conv: 1D grid 1024, bid = q*32 + n0*8 + r -> same-A blocks same XCD.
__global__ __launch_bounds__(256, 3)
void conv_kernel(const void* __restrict__ inp, int in_is_fp32,
                 const short* __restrict__ wbf, const float* __restrict__ bias,
                 void* __restrict__ outp, int out_is_bf16) {
    __shared__ short As[130 * 72];
    __shared__ short Bs[3 * 64 * 72];
    int tid = threadIdx.x, wv_ = tid >> 6, lane = tid & 63;
    int n15 = lane & 15, quad = lane >> 4;
    int bid = blockIdx.x;
    int r = bid & 7;
    int n0 = ((bid >> 3) & 3) << 6;
    int bm = (bid >> 5) * 8 + r;
    int b = bm >> 3, mt = bm & 7;
    int t0 = mt * 128;
    f32x4 acc[2][4];
    for (int i = 0; i < 2; ++i) for (int j = 0; j < 4; ++j)
        for (int p = 0; p < 4; ++p) acc[i][j][p] = 0.f;

    for (int kc = 0; kc < 4; ++kc) {
        int c0 = kc * 64;
        __syncthreads();
        if (in_is_fp32) {
            const float* in = (const float*)inp;
            for (int it = 0; it < 9; ++it) {
                int idx = tid + 256 * it;
                int row = idx >> 4, fc = idx & 15;
                if (row < 130) {
                    int t = t0 + row - 2;
                    s4v st;
                    if (t >= 0) {
                        f4 v = *reinterpret_cast<const f4*>(&in[((size_t)b * TT + t) * CC + c0 + fc * 4]);
                        for (int p = 0; p < 4; ++p) st[p] = f2bf(v[p]);
                    } else { for (int p = 0; p < 4; ++p) st[p] = 0; }
                    *reinterpret_cast<s4v*>(&As[row * 72 + fc * 4]) = st;
                }
            }
        } else {
            const short* in = (const short*)inp;
            for (int it = 0; it < 5; ++it) {
                int idx = tid + 256 * it;
                int row = idx >> 3, seg = idx & 7;
                if (row < 130) {
                    int t = t0 + row - 2;
                    s8 st;
                    if (t >= 0) st = *reinterpret_cast<const s8*>(&in[((size_t)b * TT + t) * CC + c0 + seg * 8]);
                    else for (int p = 0; p < 8; ++p) st[p] = 0;
                    *reinterpret_cast<s8*>(&As[row * 72 + seg * 8]) = st;
                }
            }
        }
        for (int it = 0; it < 6; ++it) {
            int idx = tid + 256 * it;
            int row = idx >> 3, seg = idx & 7;
            int j = row >> 6, o = row & 63;
            *reinterpret_cast<s8*>(&Bs[row * 72 + seg * 8]) =
                *reinterpret_cast<const s8*>(&wbf[((size_t)(j * 256 + n0 + o)) * 256 + c0 + seg * 8]);
        }
        __syncthreads();
        for (int j = 0; j < 3; ++j)
            for (int ks = 0; ks < 2; ++ks)
                for (int mt2 = 0; mt2 < 2; ++mt2) {
                    s8 a = *reinterpret_cast<const s8*>(&As[(wv_ * 32 + mt2 * 16 + n15 + j) * 72 + quad * 8 + ks * 32]);
                    for (int nt = 0; nt < 4; ++nt) {
                        s8 bb = *reinterpret_cast<const s8*>(&Bs[(j * 64 + nt * 16 + n15) * 72 + quad * 8 + ks * 32]);
                        acc[mt2][nt] = __builtin_amdgcn_mfma_f32_16x16x32_bf16(a, bb, acc[mt2][nt], 0, 0, 0);
                    }
                }
    }
    for (int mt2 = 0; mt2 < 2; ++mt2)
        for (int nt = 0; nt < 4; ++nt) {
            int o = n0 + nt * 16 + n15;
            float bvl = bias[o];
            for (int reg = 0; reg < 4; ++reg) {
                int t = t0 + wv_ * 32 + mt2 * 16 + quad * 4 + reg;
                float v = fmaxf(acc[mt2][nt][reg] + bvl, 0.f);
                if (out_is_bf16) ((short*)outp)[((size_t)b * TT + t) * CC + o] = f2bf(v);
                else             ((float*)outp)[((size_t)b * TT + t) * CC + o] = v;
            }
        }
}

// ---------------------------------------------------------------------------
__global__ void rowsm_kernel(const float* __restrict__ rowsum, float* __restrict__ wx) {
    __shared__ float red[256];
    int b = blockIdx.x, tid = threadIdx.x;
    float v[4];
    float m = -1e30f;
    for (int r = 0; r < 4; ++r) { v[r] = rowsum[(size_t)b * TT + tid + 256 * r]; m = fmaxf(m, v[r]); }
    red[tid] = m; __syncthreads();
    for (int s = 128; s > 0; s >>= 1) { if (tid < s) red[tid] = fmaxf(red[tid], red[tid + s]); __syncthreads(); }
    m = red[0]; __syncthreads();
    float e[4], zs = 0.f;
    for (int r = 0; r < 4; ++r) { e[r] = __expf(v[r] - m); zs += e[r]; }
    red[tid] = zs; __syncthreads();
    for (int s = 128; s > 0; s >>= 1) { if (tid < s) red[tid] += red[tid + s]; __syncthreads(); }
    float rz = 1.0f / red[0];
    for (int r = 0; r < 4; ++r) wx[(size_t)b * TT + tid + 256 * r] = e[r] * rz;
}

// ---------------------------------------------------------------------------
__global__ void final_kernel(const float* __restrict__ c2, const float* __restrict__ x,
                             const float* __restrict__ wx, float* __restrict__ out) {
    __shared__ float tile[32 * 33];
    int tid = threadIdx.x;
    int c0 = blockIdx.x * 32, t0 = blockIdx.y * 32, b = blockIdx.z;
    int tl = tid >> 3, c4 = (tid & 7) * 4;
    f4 v = *reinterpret_cast<const f4*>(&c2[((size_t)b * TT + t0 + tl) * CC + c0 + c4]);
    for (int p = 0; p < 4; ++p) tile[tl * 33 + c4 + p] = v[p];
    __syncthreads();
    int cl = tid >> 3, t4 = (tid & 7) * 4;
    f4 x4 = *reinterpret_cast<const f4*>(&x[((size_t)b * CC + c0 + cl) * TT + t0 + t4]);
    f4 w4 = *reinterpret_cast<const f4*>(&wx[(size_t)b * TT + t0 + t4]);
    f4 r;
    for (int p = 0; p < 4; ++p) {
        float cv = tile[(t4 + p) * 33 + cl];
        r[p] = fmaxf(cv + x4[p] * (1.f + w4[p]), 0.f);
    }
    *reinterpret_cast<f4*>(&out[((size_t)b * CC + c0 + cl) * TT + t0 + t4]) = r;
}

// ---------------------------------------------------------------------------
extern "C" void kernel_launch(void* const* d_in, const int* in_sizes, int n_in,
                              void* d_out, int out_size, void* d_ws, size_t ws_size,
                              hipStream_t stream) {
    (void)in_sizes; (void)n_in; (void)out_size; (void)ws_size;
    const float* x  = (const float*)d_in[0];
    const float* wq = (const float*)d_in[1];
    const float* bq = (const float*)d_in[2];
    const float* wk = (const float*)d_in[3];
    const float* bk = (const float*)d_in[4];
    const float* wv = (const float*)d_in[5];
    const float* bv = (const float*)d_in[6];
    const float* v1 = (const float*)d_in[7];
    const float* g1 = (const float*)d_in[8];
    const float* b1 = (const float*)d_in[9];
    const float* v2 = (const float*)d_in[10];
    const float* g2 = (const float*)d_in[11];
    const float* b2 = (const float*)d_in[12];
    char* ws = (char*)d_ws;
    float* out = (float*)d_out;

    short* qbf  = (short*)(ws + OFF_QBF);
    short* kbf  = (short*)(ws + OFF_KBF);
    short* vt   = (short*)(ws + OFF_VT);
    short* xt   = (short*)(ws + OFF_OA);   // xt bf16 (dead after qkv)
    short* oab  = (short*)(ws + OFF_OA);   // oa bf16 (attn out; dead after conv1)
    float* oa   = (float*)(ws + OFF_OA);   // c2 fp32 (conv2 out)
    short* c1   = (short*)(ws + OFF_C1);
    float* crz  = (float*)(ws + OFF_CRZ);
    float* rs   = (float*)(ws + OFF_RS);
    float* wxb  = (float*)(ws + OFF_WX);
    short* w1bf = (short*)(ws + OFF_W1);
    short* w2bf = (short*)(ws + OFF_W2);
    short* wqkv = (short*)(ws + OFF_WQKV);

    wn_kernel<<<dim3(512), dim3(256), 0, stream>>>(v1, g1, v2, g2, w1bf, w2bf);
    pack_kernel<<<dim3(96), dim3(256), 0, stream>>>(wq, wk, wv, wqkv);
    transpose_kernel<<<dim3(4, 16, 32), dim3(256), 0, stream>>>(x, xt);
    qkv_kernel<<<dim3(1536), dim3(256), 0, stream>>>(xt, wqkv, bq, bk, bv, qbf, kbf, vt);
    colz_kernel<<<dim3(512), dim3(512), 0, stream>>>(qbf, kbf, crz);
    attn_kernel<<<dim3(512), dim3(512), 0, stream>>>(qbf, kbf, vt, crz, oab, rs);
    conv_kernel<<<dim3(1024), dim3(256), 0, stream>>>(oab, 0, w1bf, b1, c1, 1);
    conv_kernel<<<dim3(1024), dim3(256), 0, stream>>>(c1, 0, w2bf, b2, oa, 0);
    rowsm_kernel<<<dim3(32), dim3(256), 0, stream>>>(rs, wxb);
    final_kernel<<<dim3(8, 32, 32), dim3(256), 0, stream>>>(oa, x, wxb, out);
}

// Round 10
// 253.479 us; speedup vs baseline: 1.0895x; 1.0895x over previous
//
#include <hip/hip_runtime.h>
#include <math.h>

#define BB 32
#define CC 256
#define TT 1024

typedef __attribute__((ext_vector_type(4))) float f4;
typedef __attribute__((ext_vector_type(4))) float f32x4;
typedef __attribute__((ext_vector_type(16))) float f32x16;
typedef __attribute__((ext_vector_type(8))) short s8;   // bf16x8 MFMA frag (4 VGPRs)
typedef __attribute__((ext_vector_type(4))) short s4v;  // 8B LDS store

__device__ inline short f2bf(float f) {                 // RNE fp32->bf16
    unsigned u = __builtin_bit_cast(unsigned, f);
    u = (u + 0x7FFFu + ((u >> 16) & 1u)) >> 16;
    return (short)u;
}

// ---- workspace layout (bytes) ----
static const size_t OFF_QBF  = 0;          // [B][T][64] bf16   4 MB
static const size_t OFF_KBF  = 4194304;    // [B][T][64] bf16   4 MB
static const size_t OFF_VT   = 8388608;    // [B][C][T]  bf16  16 MB (v transposed)
static const size_t OFF_OA   = 25165824;   // [B][T][C]: xt bf16 -> oa bf16 (16 MB used of 32)
static const size_t OFF_C1   = 58720256;   // [B][T][C]  bf16  16 MB (conv1 out)
static const size_t OFF_CRZ  = 75497472;   // [B][T] fp32 col 1/Z
static const size_t OFF_RS   = 75628544;   // [B][T] fp32 rowsum
static const size_t OFF_WX   = 75759616;   // [B][T] fp32 weight_x
static const size_t OFF_W1   = 75890688;   // [3][256][256] bf16 W1 [j][o][c]
static const size_t OFF_W2   = 76283904;   // [3][256][256] bf16 W2
static const size_t OFF_WQKV = 76677120;   // [384][256] bf16 (q|k|v) [n][c]

// ---------------------------------------------------------------------------
__global__ __launch_bounds__(256)
void wn_kernel(const float* __restrict__ v1, const float* __restrict__ g1,
               const float* __restrict__ v2, const float* __restrict__ g2,
               short* __restrict__ w1bf, short* __restrict__ w2bf) {
    __shared__ float red[4];
    int which = blockIdx.x >> 8, o = blockIdx.x & 255;
    const float* v = which ? v2 : v1;
    const float* g = which ? g2 : g1;
    short* wt = which ? w2bf : w1bf;
    const float* row = v + (size_t)o * 768;
    int tid = threadIdx.x, lane = tid & 63, wv_ = tid >> 6;
    float r0 = row[tid], r1 = row[tid + 256], r2 = row[tid + 512];
    float s = r0 * r0 + r1 * r1 + r2 * r2;
    for (int d = 1; d < 64; d <<= 1) s += __shfl_xor(s, d, 64);
    if (lane == 0) red[wv_] = s;
    __syncthreads();
    float scale = g[o] * rsqrtf(red[0] + red[1] + red[2] + red[3]);
    for (int j = 0; j < 3; ++j)
        wt[((size_t)(j * 256 + o)) * 256 + tid] = f2bf(scale * row[tid * 3 + j]);
}

__global__ __launch_bounds__(256)
void pack_kernel(const float* __restrict__ wq, const float* __restrict__ wk,
                 const float* __restrict__ wv, short* __restrict__ wqkvbf) {
    int n = blockIdx.x * 4 + (threadIdx.x >> 6);
    int c0 = (threadIdx.x & 63) * 4;
    for (int p = 0; p < 4; ++p) {
        int c = c0 + p;
        float w;
        if (n < 64)       w = wq[c * 64 + n];
        else if (n < 128) w = wk[c * 64 + n - 64];
        else              w = wv[c * 256 + n - 128];
        wqkvbf[(size_t)n * 256 + c] = f2bf(w);
    }
}

// ---------------------------------------------------------------------------
__global__ void transpose_kernel(const float* __restrict__ x, short* __restrict__ xt) {
    __shared__ float Tt[64 * 68];
    int tid = threadIdx.x;
    int c0 = blockIdx.x * 64, t0 = blockIdx.y * 64, b = blockIdx.z;
    for (int it = 0; it < 4; ++it) {
        int idx = tid + 256 * it;
        int cr = idx >> 4, tc = idx & 15;
        f4 v = *reinterpret_cast<const f4*>(&x[((size_t)b * CC + c0 + cr) * TT + t0 + tc * 4]);
        *reinterpret_cast<f4*>(&Tt[cr * 68 + tc * 4]) = v;
    }
    __syncthreads();
    for (int it = 0; it < 2; ++it) {
        int idx = tid + 256 * it;
        int tl = idx >> 3, seg = idx & 7;
        s8 o;
        for (int p = 0; p < 8; ++p) o[p] = f2bf(Tt[(seg * 8 + p) * 68 + tl]);
        *reinterpret_cast<s8*>(&xt[((size_t)b * TT + t0 + tl) * CC + c0 + seg * 8]) = o;
    }
}

// ---------------------------------------------------------------------------
// qkv: 1D grid 1536, bid = q*48 + n*8 + r -> same-A blocks same XCD.
__global__ __launch_bounds__(256, 3)
void qkv_kernel(const short* __restrict__ xt, const short* __restrict__ wqkv,
                const float* __restrict__ bq, const float* __restrict__ bk,
                const float* __restrict__ bv,
                short* __restrict__ qbf, short* __restrict__ kbf, short* __restrict__ vt) {
    __shared__ short SL[128 * 72 + 64 * 72];   // A (128t x 64c) then B (64n x 64c)
    short* Asm = SL;
    short* Bsm = SL + 128 * 72;
    int tid = threadIdx.x, wv_ = tid >> 6, lane = tid & 63;
    int n15 = lane & 15, quad = lane >> 4;
    int bid = blockIdx.x;
    int r = bid & 7, n = (bid >> 3) % 6, qd = bid / 48;
    int bt = qd * 8 + r;
    int b = bt >> 3, t0 = (bt & 7) * 128;
    int n0 = n * 64;

    f32x4 acc[2][4];
    for (int i = 0; i < 2; ++i) for (int j = 0; j < 4; ++j)
        for (int p = 0; p < 4; ++p) acc[i][j][p] = 0.f;

    for (int kc = 0; kc < 4; ++kc) {
        int c0 = kc * 64;
        __syncthreads();
        for (int it = 0; it < 4; ++it) {
            int idx = tid + 256 * it;
            int row = idx >> 3, seg = idx & 7;
            *reinterpret_cast<s8*>(&Asm[row * 72 + seg * 8]) =
                *reinterpret_cast<const s8*>(&xt[((size_t)b * TT + t0 + row) * CC + c0 + seg * 8]);
        }
        for (int it = 0; it < 2; ++it) {
            int idx = tid + 256 * it;
            int row = idx >> 3, seg = idx & 7;
            *reinterpret_cast<s8*>(&Bsm[row * 72 + seg * 8]) =
                *reinterpret_cast<const s8*>(&wqkv[(size_t)(n0 + row) * 256 + c0 + seg * 8]);
        }
        __syncthreads();
        for (int ks = 0; ks < 2; ++ks)
            for (int mt2 = 0; mt2 < 2; ++mt2) {
                s8 a = *reinterpret_cast<const s8*>(&Asm[(wv_ * 32 + mt2 * 16 + n15) * 72 + quad * 8 + ks * 32]);
                for (int nt = 0; nt < 4; ++nt) {
                    s8 bb = *reinterpret_cast<const s8*>(&Bsm[(nt * 16 + n15) * 72 + quad * 8 + ks * 32]);
                    acc[mt2][nt] = __builtin_amdgcn_mfma_f32_16x16x32_bf16(a, bb, acc[mt2][nt], 0, 0, 0);
                }
            }
    }
    if (n0 < 128) {
        short* outp = (n0 == 0) ? qbf : kbf;
        const float* bias = (n0 == 0) ? bq : bk;
        for (int mt2 = 0; mt2 < 2; ++mt2)
            for (int nt = 0; nt < 4; ++nt) {
                int n_ = nt * 16 + n15;
                float bvl = bias[n_];
                for (int reg = 0; reg < 4; ++reg) {
                    int t = t0 + wv_ * 32 + mt2 * 16 + quad * 4 + reg;
                    outp[((size_t)b * TT + t) * 64 + n_] = f2bf(acc[mt2][nt][reg] + bvl);
                }
            }
    } else {
        int cbase = n0 - 128;
        __syncthreads();
        short* Tw = SL + wv_ * 3072;
        for (int mt2 = 0; mt2 < 2; ++mt2)
            for (int nt = 0; nt < 4; ++nt) {
                int n_ = nt * 16 + n15;
                float bvl = bv[cbase + n_];
                for (int reg = 0; reg < 4; ++reg)
                    Tw[n_ * 48 + mt2 * 16 + quad * 4 + reg] = f2bf(acc[mt2][nt][reg] + bvl);
            }
        for (int p = 0; p < 4; ++p) {
            int n_ = (lane >> 2) + 16 * p;
            int seg = lane & 3;
            s8 vv = *reinterpret_cast<const s8*>(&Tw[n_ * 48 + seg * 8]);
            *reinterpret_cast<s8*>(&vt[((size_t)b * CC + cbase + n_) * TT + t0 + wv_ * 32 + seg * 8]) = vv;
        }
    }
}

// ---------------------------------------------------------------------------
// colz: R7 config restored (grid 256, paired {pr,15-pr}, no XCD swizzle).
__global__ __launch_bounds__(512, 2)
void colz_kernel(const short* __restrict__ qbf, const short* __restrict__ kbf,
                 float* __restrict__ colrz) {
    __shared__ short Qs[64 * 72], Ks[64 * 72];
    __shared__ float redz[8 * 32];
    int tid = threadIdx.x, wv_ = tid >> 6, lane = tid & 63;
    int l31 = lane & 31, lh = lane >> 5;
    int qhalf = wv_ & 1, khalf = (wv_ >> 1) & 1, w4 = wv_ >> 2;
    int b = blockIdx.x >> 3, pr = blockIdx.x & 7;
    int kts[2] = {pr, 15 - pr};
    int row = tid >> 3, sg = (tid & 7) * 8;

    for (int ph = 0; ph < 2; ++ph) {
        int kt = kts[ph];
        s8 kr0 = *reinterpret_cast<const s8*>(&kbf[((size_t)b * TT + kt * 64 + row) * 64 + sg]);
        s8 qr0 = *reinterpret_cast<const s8*>(&qbf[((size_t)b * TT + kt * 64 + row) * 64 + sg]);
        float zloc = 0.f;
        for (int qt = kt; qt < 16; ++qt) {
            __syncthreads();
            if (qt == kt) *reinterpret_cast<s8*>(&Ks[row * 72 + sg]) = kr0;
            *reinterpret_cast<s8*>(&Qs[row * 72 + sg]) = qr0;
            __syncthreads();
            if (qt < 15)
                qr0 = *reinterpret_cast<const s8*>(&qbf[((size_t)b * TT + (qt + 1) * 64 + row) * 64 + sg]);
            f32x16 s;
            for (int p = 0; p < 16; ++p) s[p] = 0.f;
            for (int kc = 0; kc < 4; ++kc) {
                s8 a  = *reinterpret_cast<const s8*>(&Qs[(qhalf * 32 + l31) * 72 + kc * 16 + lh * 8]);
                s8 bb = *reinterpret_cast<const s8*>(&Ks[(khalf * 32 + l31) * 72 + kc * 16 + lh * 8]);
                s = __builtin_amdgcn_mfma_f32_32x32x16_bf16(a, bb, s, 0, 0, 0);
            }
            int kg = kt * 64 + khalf * 32 + l31;
            int qb0 = qt * 64 + qhalf * 32 + 4 * lh;
            if (qt > kt) {
                for (int r = 0; r < 8; ++r) {
                    int reg = w4 * 8 + r;
                    zloc += __expf(s[reg] * 0.125f);
                }
            } else {
                for (int r = 0; r < 8; ++r) {
                    int reg = w4 * 8 + r;
                    if (qb0 + (reg & 3) + 8 * (reg >> 2) >= kg) zloc += __expf(s[reg] * 0.125f);
                }
            }
        }
        float zc = zloc + __shfl_xor(zloc, 32, 64);
        if (lane < 32) redz[wv_ * 32 + lane] = zc;
        __syncthreads();
        if (tid < 64) {
            int kh = tid >> 5, kk = tid & 31;
            float Z;
            if (kh == 0) Z = redz[0 * 32 + kk] + redz[1 * 32 + kk] + redz[4 * 32 + kk] + redz[5 * 32 + kk];
            else         Z = redz[2 * 32 + kk] + redz[3 * 32 + kk] + redz[6 * 32 + kk] + redz[7 * 32 + kk];
            colrz[(size_t)b * TT + kt * 64 + tid] = 1.0f / Z;
        }
        __syncthreads();
    }
}

// ---------------------------------------------------------------------------
// attn: R7 config restored (grid 256, paired {15-pr,pr}, NO XCD swizzle —
// R8's swizzle coincided with the 50.6->60.9 regression; this A/Bs it) with
// bf16 oab output kept (feeds conv1's bf16 staging path).
__global__ __launch_bounds__(512, 2)
void attn_kernel(const short* __restrict__ qbf, const short* __restrict__ kbf,
                 const short* __restrict__ vt, const float* __restrict__ colrz,
                 short* __restrict__ oab, float* __restrict__ rowsum) {
    __shared__ short Qs[64 * 72];
    __shared__ short Ks[64 * 72];
    __shared__ short Ps[64 * 72];   // [q][k] bf16, PV A-operand (cross-wave)
    __shared__ short Vs[256 * 72];  // [c][t_k] bf16, PV B-operand
    __shared__ float redR[2][64];
    int tid = threadIdx.x, wv_ = tid >> 6, lane = tid & 63;
    int l31 = lane & 31, lh = lane >> 5;
    int wq2 = wv_ & 1, wk2 = (wv_ >> 1) & 1, w4 = wv_ >> 2, wcq = wv_ >> 1;
    int b = blockIdx.x >> 3, pr = blockIdx.x & 7;
    int qts[2] = {15 - pr, pr};
    int row = tid >> 3, sg = (tid & 7) * 8;

    s8 kreg, vreg[4];
    {   // K/V tile kt=0
        kreg = *reinterpret_cast<const s8*>(&kbf[((size_t)b * TT + row) * 64 + sg]);
        for (int it = 0; it < 4; ++it) {
            int idx = tid + 512 * it;
            int vr = idx >> 3, seg = idx & 7;
            vreg[it] = *reinterpret_cast<const s8*>(&vt[((size_t)b * CC + vr) * TT + seg * 8]);
        }
    }

    for (int ph = 0; ph < 2; ++ph) {
        int qt = qts[ph];
        s8 qr0 = *reinterpret_cast<const s8*>(&qbf[((size_t)b * TT + qt * 64 + row) * 64 + sg]);
        f32x16 acc[2];
        for (int i = 0; i < 2; ++i) for (int p = 0; p < 16; ++p) acc[i][p] = 0.f;
        float rsum[8];
        for (int i = 0; i < 8; ++i) rsum[i] = 0.f;

        for (int kt = 0; kt <= qt; ++kt) {
            __syncthreads();
            if (kt == 0) *reinterpret_cast<s8*>(&Qs[row * 72 + sg]) = qr0;
            *reinterpret_cast<s8*>(&Ks[row * 72 + sg]) = kreg;
            for (int it = 0; it < 4; ++it) {
                int idx = tid + 512 * it;
                int vr = idx >> 3, seg = idx & 7;
                *reinterpret_cast<s8*>(&Vs[vr * 72 + seg * 8]) = vreg[it];
            }
            __syncthreads();
            int nkt = (kt < qt) ? kt + 1 : ((ph == 0) ? 0 : -1);
            if (nkt >= 0) {   // prefetch overlaps compute below
                kreg = *reinterpret_cast<const s8*>(&kbf[((size_t)b * TT + nkt * 64 + row) * 64 + sg]);
                for (int it = 0; it < 4; ++it) {
                    int idx = tid + 512 * it;
                    int vr = idx >> 3, seg = idx & 7;
                    vreg[it] = *reinterpret_cast<const s8*>(&vt[((size_t)b * CC + vr) * TT + nkt * 64 + seg * 8]);
                }
            }
            // QK quadrant (wq2, wk2), duplicated across w4 pair: 4 MFMAs
            f32x16 s;
            for (int p = 0; p < 16; ++p) s[p] = 0.f;
            for (int kc = 0; kc < 4; ++kc) {
                s8 a  = *reinterpret_cast<const s8*>(&Qs[(wq2 * 32 + l31) * 72 + kc * 16 + lh * 8]);
                s8 bb = *reinterpret_cast<const s8*>(&Ks[(wk2 * 32 + l31) * 72 + kc * 16 + lh * 8]);
                s = __builtin_amdgcn_mfma_f32_32x32x16_bf16(a, bb, s, 0, 0, 0);
            }
            int kg = kt * 64 + wk2 * 32 + l31;
            float rz = colrz[(size_t)b * TT + kg];
            bool full = (kt < qt);
            int qb0 = qt * 64 + wq2 * 32 + 4 * lh;
            for (int r = 0; r < 8; ++r) {      // exp split: w4 half of the regs
                int reg = w4 * 8 + r;
                int rr = (reg & 3) + 8 * (reg >> 2);
                float p = 0.f;
                if (full || qb0 + rr >= kg) p = __expf(s[reg] * 0.125f) * rz;
                rsum[r] += p;
                Ps[(wq2 * 32 + rr + 4 * lh) * 72 + wk2 * 32 + l31] = f2bf(p);
            }
            __syncthreads();   // Ps cross-wave
            // PV: q half wq2 x c quarter wcq: 2 tiles x 4 kc = 8 MFMAs
            for (int kc = 0; kc < 4; ++kc) {
                s8 a = *reinterpret_cast<const s8*>(&Ps[(wq2 * 32 + l31) * 72 + kc * 16 + lh * 8]);
                for (int nt = 0; nt < 2; ++nt) {
                    s8 bb = *reinterpret_cast<const s8*>(&Vs[(wcq * 64 + nt * 32 + l31) * 72 + kc * 16 + lh * 8]);
                    acc[nt] = __builtin_amdgcn_mfma_f32_32x32x16_bf16(a, bb, acc[nt], 0, 0, 0);
                }
            }
        }
        // rowsum: butterfly over the 32 k-columns, then combine wk2 halves
        for (int r = 0; r < 8; ++r) {
            float v = rsum[r];
            v += __shfl_xor(v, 1, 64);
            v += __shfl_xor(v, 2, 64);
            v += __shfl_xor(v, 4, 64);
            v += __shfl_xor(v, 8, 64);
            v += __shfl_xor(v, 16, 64);
            int reg = w4 * 8 + r;
            int rr = (reg & 3) + 8 * (reg >> 2);
            if (l31 == 0) redR[wk2][wq2 * 32 + rr + 4 * lh] = v;
        }
        for (int nt = 0; nt < 2; ++nt) {
            int c = wcq * 64 + nt * 32 + l31;
            for (int reg = 0; reg < 16; ++reg) {
                int q = qt * 64 + wq2 * 32 + (reg & 3) + 8 * (reg >> 2) + 4 * lh;
                oab[((size_t)b * TT + q) * CC + c] = f2bf(acc[nt][reg]);
            }
        }
        __syncthreads();
        if (tid < 64) rowsum[(size_t)b * TT + qt * 64 + tid] = redR[0][tid] + redR[1][tid];
        __syncthreads();
    }
}

// ---------------------------------------------------------------------------
// conv: 1D grid 1024, bid = q*32 + n0*8 + r (same-A blocks same XCD).
// R10: optional fused final epilogue (conv2): out[b,c,t] = relu(c2 + x*(1+wx))
// via LDS transpose — c2 (32 MB fp32) never touches HBM; final_kernel gone.
__global__ __launch_bounds__(256, 3)
void conv_kernel(const void* __restrict__ inp, int in_is_fp32,
                 const short* __restrict__ wbf, const float* __restrict__ bias,
                 void* __restrict__ outp, int out_is_bf16,
                 const float* __restrict__ xres, const float* __restrict__ wxv,
                 int fuse_final) {
    __shared__ short SL[130 * 72 + 3 * 64 * 72];   // As | Bs ; reused as Ft[128][67] fp32
    short* As = SL;
    short* Bs = SL + 130 * 72;
    int tid = threadIdx.x, wv_ = tid >> 6, lane = tid & 63;
    int n15 = lane & 15, quad = lane >> 4;
    int bid = blockIdx.x;
    int r = bid & 7;
    int n0 = ((bid >> 3) & 3) << 6;
    int bm = (bid >> 5) * 8 + r;
    int b = bm >> 3, mt = bm & 7;
    int t0 = mt * 128;
    f32x4 acc[2][4];
    for (int i = 0; i < 2; ++i) for (int j = 0; j < 4; ++j)
        for (int p = 0; p < 4; ++p) acc[i][j][p] = 0.f;

    for (int kc = 0; kc < 4; ++kc) {
        int c0 = kc * 64;
        __syncthreads();
        if (in_is_fp32) {
            const float* in = (const float*)inp;
            for (int it = 0; it < 9; ++it) {
                int idx = tid + 256 * it;
                int row = idx >> 4, fc = idx & 15;
                if (row < 130) {
                    int t = t0 + row - 2;
                    s4v st;
                    if (t >= 0) {
                        f4 v = *reinterpret_cast<const f4*>(&in[((size_t)b * TT + t) * CC + c0 + fc * 4]);
                        for (int p = 0; p < 4; ++p) st[p] = f2bf(v[p]);
                    } else { for (int p = 0; p < 4; ++p) st[p] = 0; }
                    *reinterpret_cast<s4v*>(&As[row * 72 + fc * 4]) = st;
                }
            }
        } else {
            const short* in = (const short*)inp;
            for (int it = 0; it < 5; ++it) {
                int idx = tid + 256 * it;
                int row = idx >> 3, seg = idx & 7;
                if (row < 130) {
                    int t = t0 + row - 2;
                    s8 st;
                    if (t >= 0) st = *reinterpret_cast<const s8*>(&in[((size_t)b * TT + t) * CC + c0 + seg * 8]);
                    else for (int p = 0; p < 8; ++p) st[p] = 0;
                    *reinterpret_cast<s8*>(&As[row * 72 + seg * 8]) = st;
                }
            }
        }
        for (int it = 0; it < 6; ++it) {
            int idx = tid + 256 * it;
            int row = idx >> 3, seg = idx & 7;
            int j = row >> 6, o = row & 63;
            *reinterpret_cast<s8*>(&Bs[row * 72 + seg * 8]) =
                *reinterpret_cast<const s8*>(&wbf[((size_t)(j * 256 + n0 + o)) * 256 + c0 + seg * 8]);
        }
        __syncthreads();
        for (int j = 0; j < 3; ++j)
            for (int ks = 0; ks < 2; ++ks)
                for (int mt2 = 0; mt2 < 2; ++mt2) {
                    s8 a = *reinterpret_cast<const s8*>(&As[(wv_ * 32 + mt2 * 16 + n15 + j) * 72 + quad * 8 + ks * 32]);
                    for (int nt = 0; nt < 4; ++nt) {
                        s8 bb = *reinterpret_cast<const s8*>(&Bs[(j * 64 + nt * 16 + n15) * 72 + quad * 8 + ks * 32]);
                        acc[mt2][nt] = __builtin_amdgcn_mfma_f32_16x16x32_bf16(a, bb, acc[mt2][nt], 0, 0, 0);
                    }
                }
    }
    if (!fuse_final) {
        for (int mt2 = 0; mt2 < 2; ++mt2)
            for (int nt = 0; nt < 4; ++nt) {
                int o = n0 + nt * 16 + n15;
                float bvl = bias[o];
                for (int reg = 0; reg < 4; ++reg) {
                    int t = t0 + wv_ * 32 + mt2 * 16 + quad * 4 + reg;
                    float v = fmaxf(acc[mt2][nt][reg] + bvl, 0.f);
                    if (out_is_bf16) ((short*)outp)[((size_t)b * TT + t) * CC + o] = f2bf(v);
                    else             ((float*)outp)[((size_t)b * TT + t) * CC + o] = v;
                }
            }
    } else {
        float* Ft = (float*)SL;            // [128][67] fp32 (34304 B <= SL)
        __syncthreads();                   // all LDS reads of As/Bs done
        for (int mt2 = 0; mt2 < 2; ++mt2)
            for (int nt = 0; nt < 4; ++nt) {
                int ol = nt * 16 + n15;
                float bvl = bias[n0 + ol];
                for (int reg = 0; reg < 4; ++reg) {
                    int tl = wv_ * 32 + mt2 * 16 + quad * 4 + reg;
                    Ft[tl * 67 + ol] = fmaxf(acc[mt2][nt][reg] + bvl, 0.f);
                }
            }
        __syncthreads();
        int c_l = tid >> 5;                // 0..7
        int t_l = (tid & 31) * 4;          // 0..124
        f4 wv4 = *reinterpret_cast<const f4*>(&wxv[(size_t)b * TT + t0 + t_l]);
        for (int pass = 0; pass < 8; ++pass) {
            int c = n0 + pass * 8 + c_l;
            f4 xv = *reinterpret_cast<const f4*>(&xres[((size_t)b * CC + c) * TT + t0 + t_l]);
            f4 rr;
            for (int p = 0; p < 4; ++p)
                rr[p] = fmaxf(Ft[(t_l + p) * 67 + pass * 8 + c_l] + xv[p] * (1.f + wv4[p]), 0.f);
            *reinterpret_cast<f4*>(&((float*)outp)[((size_t)b * CC + c) * TT + t0 + t_l]) = rr;
        }
    }
}

// ---------------------------------------------------------------------------
__global__ void rowsm_kernel(const float* __restrict__ rowsum, float* __restrict__ wx) {
    __shared__ float red[256];
    int b = blockIdx.x, tid = threadIdx.x;
    float v[4];
    float m = -1e30f;
    for (int r = 0; r < 4; ++r) { v[r] = rowsum[(size_t)b * TT + tid + 256 * r]; m = fmaxf(m, v[r]); }
    red[tid] = m; __syncthreads();
    for (int s = 128; s > 0; s >>= 1) { if (tid < s) red[tid] = fmaxf(red[tid], red[tid + s]); __syncthreads(); }
    m = red[0]; __syncthreads();
    float e[4], zs = 0.f;
    for (int r = 0; r < 4; ++r) { e[r] = __expf(v[r] - m); zs += e[r]; }
    red[tid] = zs; __syncthreads();
    for (int s = 128; s > 0; s >>= 1) { if (tid < s) red[tid] += red[tid + s]; __syncthreads(); }
    float rz = 1.0f / red[0];
    for (int r = 0; r < 4; ++r) wx[(size_t)b * TT + tid + 256 * r] = e[r] * rz;
}

// ---------------------------------------------------------------------------
extern "C" void kernel_launch(void* const* d_in, const int* in_sizes, int n_in,
                              void* d_out, int out_size, void* d_ws, size_t ws_size,
                              hipStream_t stream) {
    (void)in_sizes; (void)n_in; (void)out_size; (void)ws_size;
    const float* x  = (const float*)d_in[0];
    const float* wq = (const float*)d_in[1];
    const float* bq = (const float*)d_in[2];
    const float* wk = (const float*)d_in[3];
    const float* bk = (const float*)d_in[4];
    const float* wv = (const float*)d_in[5];
    const float* bv = (const float*)d_in[6];
    const float* v1 = (const float*)d_in[7];
    const float* g1 = (const float*)d_in[8];
    const float* b1 = (const float*)d_in[9];
    const float* v2 = (const float*)d_in[10];
    const float* g2 = (const float*)d_in[11];
    const float* b2 = (const float*)d_in[12];
    char* ws = (char*)d_ws;
    float* out = (float*)d_out;

    short* qbf  = (short*)(ws + OFF_QBF);
    short* kbf  = (short*)(ws + OFF_KBF);
    short* vt   = (short*)(ws + OFF_VT);
    short* xt   = (short*)(ws + OFF_OA);   // xt bf16 (dead after qkv)
    short* oab  = (short*)(ws + OFF_OA);   // oa bf16 (attn out; dead after conv1)
    short* c1   = (short*)(ws + OFF_C1);
    float* crz  = (float*)(ws + OFF_CRZ);
    float* rs   = (float*)(ws + OFF_RS);
    float* wxb  = (float*)(ws + OFF_WX);
    short* w1bf = (short*)(ws + OFF_W1);
    short* w2bf = (short*)(ws + OFF_W2);
    short* wqkv = (short*)(ws + OFF_WQKV);

    wn_kernel<<<dim3(512), dim3(256), 0, stream>>>(v1, g1, v2, g2, w1bf, w2bf);
    pack_kernel<<<dim3(96), dim3(256), 0, stream>>>(wq, wk, wv, wqkv);
    transpose_kernel<<<dim3(4, 16, 32), dim3(256), 0, stream>>>(x, xt);
    qkv_kernel<<<dim3(1536), dim3(256), 0, stream>>>(xt, wqkv, bq, bk, bv, qbf, kbf, vt);
    colz_kernel<<<dim3(256), dim3(512), 0, stream>>>(qbf, kbf, crz);
    attn_kernel<<<dim3(256), dim3(512), 0, stream>>>(qbf, kbf, vt, crz, oab, rs);
    rowsm_kernel<<<dim3(32), dim3(256), 0, stream>>>(rs, wxb);
    conv_kernel<<<dim3(1024), dim3(256), 0, stream>>>(oab, 0, w1bf, b1, c1, 1,
                                                      nullptr, nullptr, 0);
    conv_kernel<<<dim3(1024), dim3(256), 0, stream>>>(c1, 0, w2bf, b2, out, 0,
                                                      x, wxb, 1);
}